// Round 9
// baseline (469.080 us; speedup 1.0000x reference)
//
#include <hip/hip_runtime.h>
#include <hip/hip_bf16.h>

#define TT 8192
#define DD 2048
#define HH 1408
#define EE 8
#define KTOP 2
#define NA (TT * KTOP)  // 16384 assignments

typedef __attribute__((ext_vector_type(8))) short bh8;   // 8 bf16 = 4 VGPR
typedef __attribute__((ext_vector_type(4))) float f4;    // MFMA accumulator

typedef __attribute__((address_space(1))) const void gconst_t;
typedef __attribute__((address_space(3))) void lds_t;

__device__ __forceinline__ void glds16(const void* g, void* l) {
  __builtin_amdgcn_global_load_lds((gconst_t*)g, (lds_t*)l, 16, 0, 0);
}

__device__ __forceinline__ float silu_f(float x) { return x / (1.f + __expf(-x)); }

__device__ __forceinline__ unsigned bf16_bits(float x) {
  __hip_bfloat16 h = __float2bfloat16(x);
  return (unsigned)*reinterpret_cast<unsigned short*>(&h);
}

// ---------------- fused bookkeeping: count + scan + scatter, one block ----------------
__global__ __launch_bounds__(1024) void k_book(const int* __restrict__ idx,
                                               const float* __restrict__ sc,
                                               int* __restrict__ off,
                                               int* __restrict__ rows_token,
                                               float* __restrict__ rows_score,
                                               int* __restrict__ pos) {
  __shared__ int cnt[EE];
  __shared__ int cur[EE];
  __shared__ int offs[EE + 1];
  const int tid = threadIdx.x;
  if (tid < EE) cnt[tid] = 0;
  __syncthreads();
#pragma unroll
  for (int j = 0; j < NA / 1024; ++j)
    atomicAdd(&cnt[idx[tid + j * 1024]], 1);
  __syncthreads();
  if (tid == 0) {
    int a = 0;
    for (int e = 0; e < EE; ++e) { offs[e] = a; cur[e] = a; a += cnt[e]; }
    offs[EE] = a;
  }
  __syncthreads();
  if (tid <= EE) off[tid] = offs[tid];
#pragma unroll
  for (int j = 0; j < NA / 1024; ++j) {
    int i = tid + j * 1024;
    int e = idx[i];
    int p = atomicAdd(&cur[e], 1);
    rows_token[p] = i >> 1;  // KTOP == 2
    rows_score[p] = sc[i];
    pos[i] = p;
  }
}

// ---------------- fused prep v3 ----------------
// 256 threads. blocks [0,1024): x fp32->bf16 streaming (16 float4/thread).
// blocks [1024,6656): Wg/Wu transpose, 64 src-rows x 128 src-cols tiles.
// blocks [6656,9472): Wd transpose.
// LDS [64][129] fp32: write-phase reads t[2l][j] / t[2l+1][j] with half-wave
// rows j / j+1 -> exactly 2 lanes/bank (free, m136). Stores: 32 lanes write
// one 128B contiguous out-row segment (u32 = packed bf16 pair).
__global__ __launch_bounds__(256) void k_prep(
    const float* __restrict__ x, __hip_bfloat16* __restrict__ xb,
    const float* __restrict__ Wg, const float* __restrict__ Wu,
    const float* __restrict__ Wd, __hip_bfloat16* __restrict__ Wgb,
    __hip_bfloat16* __restrict__ Wub, __hip_bfloat16* __restrict__ Wdb) {
  const int bid = blockIdx.x;
  const int tid = threadIdx.x;
  if (bid < 1024) {
    const float4* s4 = reinterpret_cast<const float4*>(x);
#pragma unroll
    for (int j = 0; j < 16; ++j) {
      int i = bid * 4096 + j * 256 + tid;
      float4 v = s4[i];
      union { ushort4 u; __hip_bfloat16 h[4]; } o;
      o.h[0] = __float2bfloat16(v.x); o.h[1] = __float2bfloat16(v.y);
      o.h[2] = __float2bfloat16(v.z); o.h[3] = __float2bfloat16(v.w);
      reinterpret_cast<ushort4*>(xb)[i] = o.u;
    }
    return;
  }
  __shared__ float t[64][129];
  const float* s;
  __hip_bfloat16* d;
  int R, C, rt, ct;
  if (bid < 6656) {
    int tno = bid - 1024;
    ct = tno % 11; tno /= 11;      // 11 col-tiles of 128 over HH
    rt = tno % 32; tno /= 32;      // 32 row-tiles of 64 over DD
    int e = tno & 7, sel = tno >> 3;
    R = DD; C = HH;
    s = (sel ? Wu : Wg) + (size_t)e * DD * HH;
    d = (sel ? Wub : Wgb) + (size_t)e * DD * HH;
  } else {
    int tno = bid - 6656;
    ct = tno % 16; tno /= 16;      // 16 col-tiles of 128 over DD
    rt = tno % 22; tno /= 22;      // 22 row-tiles of 64 over HH
    int e = tno;
    R = HH; C = DD;
    s = Wd + (size_t)e * DD * HH;
    d = Wdb + (size_t)e * DD * HH;
  }
  const int c0 = ct * 128, r0 = rt * 64;
  // read: 64 rows x 512B, coalesced (wave = 2 rows x 32 float4)
#pragma unroll
  for (int j = 0; j < 8; ++j) {
    int f = tid + 256 * j;
    int row = f >> 5, c4 = (f & 31) << 2;
    float4 v = *reinterpret_cast<const float4*>(&s[(size_t)(r0 + row) * C + c0 + c4]);
    t[row][c4] = v.x; t[row][c4 + 1] = v.y; t[row][c4 + 2] = v.z; t[row][c4 + 3] = v.w;
  }
  __syncthreads();
  // write: out-row j (src col), 32 lanes x u32 = 128B contiguous per row
#pragma unroll
  for (int pp = 0; pp < 16; ++pp) {
    int g = pp * 256 + tid;
    int j = g >> 5, l = g & 31;
    unsigned lo = bf16_bits(t[2 * l][j]);
    unsigned hi = bf16_bits(t[2 * l + 1][j]);
    unsigned* dp = reinterpret_cast<unsigned*>(d + (size_t)(c0 + j) * R + r0);
    dp[l] = lo | (hi << 16);
  }
}

// combine: y[t] = fp32(ybuf[pos[2t]]) + fp32(ybuf[pos[2t+1]])  (scores pre-folded)
__global__ void k_combine(const __hip_bfloat16* __restrict__ ybuf,
                          const int* __restrict__ pos, float* __restrict__ y) {
  int i = blockIdx.x * 256 + threadIdx.x;  // over TT * DD/8
  int t = i >> 8;                          // DD/8 == 256
  int d0 = (i & 255) << 3;
  const uint4 a = *reinterpret_cast<const uint4*>(ybuf + (size_t)pos[2 * t] * DD + d0);
  const uint4 b = *reinterpret_cast<const uint4*>(ybuf + (size_t)pos[2 * t + 1] * DD + d0);
  float* o = y + (size_t)t * DD + d0;
  unsigned au[4] = {a.x, a.y, a.z, a.w}, bu[4] = {b.x, b.y, b.z, b.w};
  float r[8];
#pragma unroll
  for (int j = 0; j < 4; ++j) {
    r[2 * j] = __uint_as_float(au[j] << 16) + __uint_as_float(bu[j] << 16);
    r[2 * j + 1] = __uint_as_float(au[j] & 0xffff0000u) + __uint_as_float(bu[j] & 0xffff0000u);
  }
  reinterpret_cast<float4*>(o)[0] = (float4){r[0], r[1], r[2], r[3]};
  reinterpret_cast<float4*>(o)[1] = (float4){r[4], r[5], r[6], r[7]};
}

// ---------------- GEMM1: h = silu(Xe*Wg) * (Xe*Wu) ----------------
// 128 rows x 128 B-cols (64 h x {gate,up}), BK=64, 4 waves in 2x2 QUADRANTS
// (64x64 per wave): a[4]+b[4] per kk -> 16 MFMA = 2 MFMA per ds_read (optimal).
// B-row bn -> tensor=(bn>>4)&1, h=n0+((bn>>5)<<4)+(bn&15): silu pairing stays
// wave-local as acc[mf][2jn] (gate) / acc[mf][2jn+1] (up).
__global__ __launch_bounds__(256, 2) void k_gemm1(
    const __hip_bfloat16* __restrict__ xb,
    const __hip_bfloat16* __restrict__ Wgb,
    const __hip_bfloat16* __restrict__ Wub,
    const int* __restrict__ rows_token,
    const int* __restrict__ off,
    __hip_bfloat16* __restrict__ hbuf) {
  const int e = blockIdx.z;
  const int oe = off[e];
  const int ne = off[e + 1] - oe;
  if (ne <= 0) return;
  const int n0 = blockIdx.x * 64;
  const int tid = threadIdx.x;
  const int lane = tid & 63;
  const int w = tid >> 6;
  const int wm = w >> 1, wn = w & 1;
  const int l15 = lane & 15;
  const int l4 = lane >> 4;

  __shared__ __hip_bfloat16 As[128 * 64];
  __shared__ __hip_bfloat16 Bs[128 * 64];

  const int kel = (((lane & 7) ^ (lane >> 3)) << 3);

  const __hip_bfloat16* bsrc[4];
#pragma unroll
  for (int i = 0; i < 4; ++i) {
    int bn = ((w * 4 + i) << 3) + (lane >> 3);
    int ts = (bn >> 4) & 1;
    int hc = n0 + ((bn >> 5) << 4) + (bn & 15);
    bsrc[i] = (ts ? Wub : Wgb) + ((size_t)e * HH + hc) * DD + kel;
  }

  for (int m0 = blockIdx.y * 128; m0 < ne; m0 += gridDim.y * 128) {
    const __hip_bfloat16* asrc[4];
#pragma unroll
    for (int i = 0; i < 4; ++i) {
      int r = ((w * 4 + i) << 3) + (lane >> 3);
      int rr = m0 + r; rr = rr < ne ? rr : ne - 1;
      asrc[i] = xb + (size_t)rows_token[oe + rr] * DD + kel;
    }

    f4 acc[4][4];
#pragma unroll
    for (int mf = 0; mf < 4; ++mf)
#pragma unroll
      for (int nf = 0; nf < 4; ++nf)
        acc[mf][nf] = (f4){0.f, 0.f, 0.f, 0.f};

    for (int k0 = 0; k0 < DD; k0 += 64) {
#pragma unroll
      for (int i = 0; i < 4; ++i) {
        glds16(asrc[i] + k0, As + ((w * 4 + i) << 9));
        glds16(bsrc[i] + k0, Bs + ((w * 4 + i) << 9));
      }
      __syncthreads();
#pragma unroll
      for (int kk = 0; kk < 2; ++kk) {
        const int kByte = (kk * 32 + (l4 << 3)) * 2;
        bh8 a[4], b[4];
#pragma unroll
        for (int i = 0; i < 4; ++i) {
          int row = (wm << 6) + (i << 4) + l15;
          int ad = row * 128 + (kByte ^ ((row & 7) << 4));
          a[i] = *reinterpret_cast<const bh8*>(reinterpret_cast<const char*>(As) + ad);
        }
#pragma unroll
        for (int i = 0; i < 4; ++i) {
          int bn = (wn << 6) + (i << 4) + l15;
          int ad = bn * 128 + (kByte ^ ((bn & 7) << 4));
          b[i] = *reinterpret_cast<const bh8*>(reinterpret_cast<const char*>(Bs) + ad);
        }
#pragma unroll
        for (int mf = 0; mf < 4; ++mf)
#pragma unroll
          for (int nf = 0; nf < 4; ++nf)
            acc[mf][nf] = __builtin_amdgcn_mfma_f32_16x16x32_bf16(a[mf], b[nf], acc[mf][nf], 0, 0, 0);
      }
      __syncthreads();
    }

    // epilogue: silu(gate)*up; fragment nf: tensor=nf&1, h=n0+32*wn+16*(nf>>1)
#pragma unroll
    for (int mf = 0; mf < 4; ++mf) {
#pragma unroll
      for (int reg = 0; reg < 4; ++reg) {
        int grow = m0 + (wm << 6) + (mf << 4) + (l4 << 2) + reg;
        if (grow < ne) {
          size_t hb = (size_t)(oe + grow) * HH;
#pragma unroll
          for (int jn = 0; jn < 2; ++jn) {
            float g = acc[mf][2 * jn][reg];
            float u = acc[mf][2 * jn + 1][reg];
            hbuf[hb + n0 + 32 * wn + 16 * jn + l15] = __float2bfloat16(silu_f(g) * u);
          }
        }
      }
    }
  }
}

// ---------------- GEMM2: ybuf[row] = score * (h_e * Wd_e) in bf16 ----------------
// Same quadrant structure; B-cols map linearly (bn -> n0+bn).
__global__ __launch_bounds__(256, 2) void k_gemm2(
    const __hip_bfloat16* __restrict__ hbuf,
    const __hip_bfloat16* __restrict__ Wdb,
    const float* __restrict__ rows_score,
    const int* __restrict__ off,
    __hip_bfloat16* __restrict__ ybuf) {
  const int e = blockIdx.z;
  const int oe = off[e];
  const int ne = off[e + 1] - oe;
  if (ne <= 0) return;
  const int n0 = blockIdx.x * 128;
  const int tid = threadIdx.x;
  const int lane = tid & 63;
  const int w = tid >> 6;
  const int wm = w >> 1, wn = w & 1;
  const int l15 = lane & 15;
  const int l4 = lane >> 4;

  __shared__ __hip_bfloat16 As[128 * 64];
  __shared__ __hip_bfloat16 Bs[128 * 64];
  const int kel = (((lane & 7) ^ (lane >> 3)) << 3);

  const __hip_bfloat16* bsrc[4];
#pragma unroll
  for (int i = 0; i < 4; ++i) {
    int bn = ((w * 4 + i) << 3) + (lane >> 3);
    bsrc[i] = Wdb + ((size_t)e * DD + (n0 + bn)) * HH + kel;
  }

  for (int m0 = blockIdx.y * 128; m0 < ne; m0 += gridDim.y * 128) {
    const __hip_bfloat16* asrc[4];
#pragma unroll
    for (int i = 0; i < 4; ++i) {
      int r = ((w * 4 + i) << 3) + (lane >> 3);
      int rr = m0 + r; rr = rr < ne ? rr : ne - 1;
      asrc[i] = hbuf + (size_t)(oe + rr) * HH + kel;
    }

    f4 acc[4][4];
#pragma unroll
    for (int mf = 0; mf < 4; ++mf)
#pragma unroll
      for (int nf = 0; nf < 4; ++nf)
        acc[mf][nf] = (f4){0.f, 0.f, 0.f, 0.f};

    for (int k0 = 0; k0 < HH; k0 += 64) {
#pragma unroll
      for (int i = 0; i < 4; ++i) {
        glds16(asrc[i] + k0, As + ((w * 4 + i) << 9));
        glds16(bsrc[i] + k0, Bs + ((w * 4 + i) << 9));
      }
      __syncthreads();
#pragma unroll
      for (int kk = 0; kk < 2; ++kk) {
        const int kByte = (kk * 32 + (l4 << 3)) * 2;
        bh8 a[4], b[4];
#pragma unroll
        for (int i = 0; i < 4; ++i) {
          int row = (wm << 6) + (i << 4) + l15;
          int ad = row * 128 + (kByte ^ ((row & 7) << 4));
          a[i] = *reinterpret_cast<const bh8*>(reinterpret_cast<const char*>(As) + ad);
        }
#pragma unroll
        for (int i = 0; i < 4; ++i) {
          int bn = (wn << 6) + (i << 4) + l15;
          int ad = bn * 128 + (kByte ^ ((bn & 7) << 4));
          b[i] = *reinterpret_cast<const bh8*>(reinterpret_cast<const char*>(Bs) + ad);
        }
#pragma unroll
        for (int mf = 0; mf < 4; ++mf)
#pragma unroll
          for (int nf = 0; nf < 4; ++nf)
            acc[mf][nf] = __builtin_amdgcn_mfma_f32_16x16x32_bf16(a[mf], b[nf], acc[mf][nf], 0, 0, 0);
      }
      __syncthreads();
    }

    // epilogue: scale by gate score, write bf16 row (combined later)
#pragma unroll
    for (int mf = 0; mf < 4; ++mf) {
#pragma unroll
      for (int reg = 0; reg < 4; ++reg) {
        int grow = m0 + (wm << 6) + (mf << 4) + (l4 << 2) + reg;
        if (grow < ne) {
          float sc = rows_score[oe + grow];
          __hip_bfloat16* yr = ybuf + (size_t)(oe + grow) * DD + n0 + (wn << 6) + l15;
#pragma unroll
          for (int nf = 0; nf < 4; ++nf)
            yr[nf * 16] = __float2bfloat16(sc * acc[mf][nf][reg]);
        }
      }
    }
  }
}

// ---------------- launch ----------------
extern "C" void kernel_launch(void* const* d_in, const int* in_sizes, int n_in,
                              void* d_out, int out_size, void* d_ws, size_t ws_size,
                              hipStream_t stream) {
  const float* x = (const float*)d_in[0];
  const int* topk_idx = (const int*)d_in[1];
  const float* topk_sc = (const float*)d_in[2];
  const float* Wg = (const float*)d_in[3];
  const float* Wu = (const float*)d_in[4];
  const float* Wd = (const float*)d_in[5];
  float* y = (float*)d_out;

  char* p = (char*)d_ws;
  auto take = [&](size_t b) { char* r = p; p += (b + 255) & ~(size_t)255; return r; };
  int* off = (int*)take((EE + 1) * 4);
  int* rows_token = (int*)take((size_t)NA * 4);
  float* rows_score = (float*)take((size_t)NA * 4);
  int* pos = (int*)take((size_t)NA * 4);
  __hip_bfloat16* xb = (__hip_bfloat16*)take((size_t)TT * DD * 2);
  __hip_bfloat16* Wgb = (__hip_bfloat16*)take((size_t)EE * DD * HH * 2);
  __hip_bfloat16* Wub = (__hip_bfloat16*)take((size_t)EE * DD * HH * 2);
  __hip_bfloat16* Wdb = (__hip_bfloat16*)take((size_t)EE * DD * HH * 2);
  __hip_bfloat16* hbuf = (__hip_bfloat16*)take((size_t)NA * HH * 2);
  __hip_bfloat16* ybuf = (__hip_bfloat16*)take((size_t)NA * DD * 2);

  k_book<<<1, 1024, 0, stream>>>(topk_idx, topk_sc, off, rows_token, rows_score, pos);
  k_prep<<<9472, 256, 0, stream>>>(x, xb, Wg, Wu, Wd, Wgb, Wub, Wdb);
  k_gemm1<<<dim3(HH / 64, 17, EE), 256, 0, stream>>>(xb, Wgb, Wub, rows_token, off, hbuf);
  k_gemm2<<<dim3(DD / 128, 17, EE), 256, 0, stream>>>(hbuf, Wdb, rows_score, off, ybuf);
  k_combine<<<TT * (DD / 8) / 256, 256, 0, stream>>>(ybuf, pos, y);
}

// Round 10
// 463.703 us; speedup vs baseline: 1.0116x; 1.0116x over previous
//
#include <hip/hip_runtime.h>
#include <hip/hip_bf16.h>

#define TT 8192
#define DD 2048
#define HH 1408
#define EE 8
#define KTOP 2
#define NA (TT * KTOP)  // 16384 assignments

typedef __attribute__((ext_vector_type(8))) short bh8;   // 8 bf16 = 4 VGPR
typedef __attribute__((ext_vector_type(4))) float f4;    // MFMA accumulator

typedef __attribute__((address_space(1))) const void gconst_t;
typedef __attribute__((address_space(3))) void lds_t;

__device__ __forceinline__ void glds16(const void* g, void* l) {
  __builtin_amdgcn_global_load_lds((gconst_t*)g, (lds_t*)l, 16, 0, 0);
}

__device__ __forceinline__ float silu_f(float x) { return x / (1.f + __expf(-x)); }

__device__ __forceinline__ unsigned bf16_bits(float x) {
  __hip_bfloat16 h = __float2bfloat16(x);
  return (unsigned)*reinterpret_cast<unsigned short*>(&h);
}

// ---------------- fused bookkeeping: count + scan + scatter, one block ----------------
__global__ __launch_bounds__(1024) void k_book(const int* __restrict__ idx,
                                               const float* __restrict__ sc,
                                               int* __restrict__ off,
                                               int* __restrict__ rows_token,
                                               float* __restrict__ rows_score,
                                               int* __restrict__ pos) {
  __shared__ int cnt[EE];
  __shared__ int cur[EE];
  __shared__ int offs[EE + 1];
  const int tid = threadIdx.x;
  if (tid < EE) cnt[tid] = 0;
  __syncthreads();
#pragma unroll
  for (int j = 0; j < NA / 1024; ++j)
    atomicAdd(&cnt[idx[tid + j * 1024]], 1);
  __syncthreads();
  if (tid == 0) {
    int a = 0;
    for (int e = 0; e < EE; ++e) { offs[e] = a; cur[e] = a; a += cnt[e]; }
    offs[EE] = a;
  }
  __syncthreads();
  if (tid <= EE) off[tid] = offs[tid];
#pragma unroll
  for (int j = 0; j < NA / 1024; ++j) {
    int i = tid + j * 1024;
    int e = idx[i];
    int p = atomicAdd(&cur[e], 1);
    rows_token[p] = i >> 1;  // KTOP == 2
    rows_score[p] = sc[i];
    pos[i] = p;
  }
}

// ---------------- fused prep v3 (round-9, kept) ----------------
__global__ __launch_bounds__(256) void k_prep(
    const float* __restrict__ x, __hip_bfloat16* __restrict__ xb,
    const float* __restrict__ Wg, const float* __restrict__ Wu,
    const float* __restrict__ Wd, __hip_bfloat16* __restrict__ Wgb,
    __hip_bfloat16* __restrict__ Wub, __hip_bfloat16* __restrict__ Wdb) {
  const int bid = blockIdx.x;
  const int tid = threadIdx.x;
  if (bid < 1024) {
    const float4* s4 = reinterpret_cast<const float4*>(x);
#pragma unroll
    for (int j = 0; j < 16; ++j) {
      int i = bid * 4096 + j * 256 + tid;
      float4 v = s4[i];
      union { ushort4 u; __hip_bfloat16 h[4]; } o;
      o.h[0] = __float2bfloat16(v.x); o.h[1] = __float2bfloat16(v.y);
      o.h[2] = __float2bfloat16(v.z); o.h[3] = __float2bfloat16(v.w);
      reinterpret_cast<ushort4*>(xb)[i] = o.u;
    }
    return;
  }
  __shared__ float t[64][129];
  const float* s;
  __hip_bfloat16* d;
  int R, C, rt, ct;
  if (bid < 6656) {
    int tno = bid - 1024;
    ct = tno % 11; tno /= 11;      // 11 col-tiles of 128 over HH
    rt = tno % 32; tno /= 32;      // 32 row-tiles of 64 over DD
    int e = tno & 7, sel = tno >> 3;
    R = DD; C = HH;
    s = (sel ? Wu : Wg) + (size_t)e * DD * HH;
    d = (sel ? Wub : Wgb) + (size_t)e * DD * HH;
  } else {
    int tno = bid - 6656;
    ct = tno % 16; tno /= 16;      // 16 col-tiles of 128 over DD
    rt = tno % 22; tno /= 22;      // 22 row-tiles of 64 over HH
    int e = tno;
    R = HH; C = DD;
    s = Wd + (size_t)e * DD * HH;
    d = Wdb + (size_t)e * DD * HH;
  }
  const int c0 = ct * 128, r0 = rt * 64;
#pragma unroll
  for (int j = 0; j < 8; ++j) {
    int f = tid + 256 * j;
    int row = f >> 5, c4 = (f & 31) << 2;
    float4 v = *reinterpret_cast<const float4*>(&s[(size_t)(r0 + row) * C + c0 + c4]);
    t[row][c4] = v.x; t[row][c4 + 1] = v.y; t[row][c4 + 2] = v.z; t[row][c4 + 3] = v.w;
  }
  __syncthreads();
#pragma unroll
  for (int pp = 0; pp < 16; ++pp) {
    int g = pp * 256 + tid;
    int j = g >> 5, l = g & 31;
    unsigned lo = bf16_bits(t[2 * l][j]);
    unsigned hi = bf16_bits(t[2 * l + 1][j]);
    unsigned* dp = reinterpret_cast<unsigned*>(d + (size_t)(c0 + j) * R + r0);
    dp[l] = lo | (hi << 16);
  }
}

// combine: y[t] = fp32(ybuf[pos[2t]]) + fp32(ybuf[pos[2t+1]])  (scores pre-folded)
__global__ void k_combine(const __hip_bfloat16* __restrict__ ybuf,
                          const int* __restrict__ pos, float* __restrict__ y) {
  int i = blockIdx.x * 256 + threadIdx.x;  // over TT * DD/8
  int t = i >> 8;                          // DD/8 == 256
  int d0 = (i & 255) << 3;
  const uint4 a = *reinterpret_cast<const uint4*>(ybuf + (size_t)pos[2 * t] * DD + d0);
  const uint4 b = *reinterpret_cast<const uint4*>(ybuf + (size_t)pos[2 * t + 1] * DD + d0);
  float* o = y + (size_t)t * DD + d0;
  unsigned au[4] = {a.x, a.y, a.z, a.w}, bu[4] = {b.x, b.y, b.z, b.w};
  float r[8];
#pragma unroll
  for (int j = 0; j < 4; ++j) {
    r[2 * j] = __uint_as_float(au[j] << 16) + __uint_as_float(bu[j] << 16);
    r[2 * j + 1] = __uint_as_float(au[j] & 0xffff0000u) + __uint_as_float(bu[j] & 0xffff0000u);
  }
  reinterpret_cast<float4*>(o)[0] = (float4){r[0], r[1], r[2], r[3]};
  reinterpret_cast<float4*>(o)[1] = (float4){r[4], r[5], r[6], r[7]};
}

// ---------------- GEMM1: h = silu(Xe*Wg) * (Xe*Wu) ----------------
// Round-5 proven mapping (session-best 223us, MfmaUtil 38.6%): 128 rows x
// (64 gate + 64 up cols), BK=64, 4 waves each 32 rows x 128 cols.
__global__ __launch_bounds__(256, 2) void k_gemm1(
    const __hip_bfloat16* __restrict__ xb,
    const __hip_bfloat16* __restrict__ Wgb,
    const __hip_bfloat16* __restrict__ Wub,
    const int* __restrict__ rows_token,
    const int* __restrict__ off,
    __hip_bfloat16* __restrict__ hbuf) {
  const int e = blockIdx.z;
  const int oe = off[e];
  const int ne = off[e + 1] - oe;
  if (ne <= 0) return;
  const int n0 = blockIdx.x * 64;
  const int tid = threadIdx.x;
  const int lane = tid & 63;
  const int w = tid >> 6;

  __shared__ __hip_bfloat16 As[128 * 64];
  __shared__ __hip_bfloat16 Bs[128 * 64];

  const int kel = (((lane & 7) ^ (lane >> 3)) << 3);

  const __hip_bfloat16* bsrc[4];
#pragma unroll
  for (int i = 0; i < 4; ++i) {
    int bn = ((w * 4 + i) << 3) + (lane >> 3);
    const __hip_bfloat16* base =
        (bn < 64) ? (Wgb + ((size_t)e * HH + (n0 + bn)) * DD)
                  : (Wub + ((size_t)e * HH + (n0 + bn - 64)) * DD);
    bsrc[i] = base + kel;
  }

  for (int m0 = blockIdx.y * 128; m0 < ne; m0 += gridDim.y * 128) {
    const __hip_bfloat16* asrc[4];
#pragma unroll
    for (int i = 0; i < 4; ++i) {
      int r = ((w * 4 + i) << 3) + (lane >> 3);
      int rr = m0 + r; rr = rr < ne ? rr : ne - 1;
      asrc[i] = xb + (size_t)rows_token[oe + rr] * DD + kel;
    }

    f4 acc[2][8];
#pragma unroll
    for (int mf = 0; mf < 2; ++mf)
#pragma unroll
      for (int nf = 0; nf < 8; ++nf)
        acc[mf][nf] = (f4){0.f, 0.f, 0.f, 0.f};

    for (int k0 = 0; k0 < DD; k0 += 64) {
#pragma unroll
      for (int i = 0; i < 4; ++i) {
        glds16(asrc[i] + k0, As + ((w * 4 + i) << 9));
        glds16(bsrc[i] + k0, Bs + ((w * 4 + i) << 9));
      }
      __syncthreads();
#pragma unroll
      for (int kk = 0; kk < 2; ++kk) {
        const int kByte = (kk * 32 + ((lane >> 4) << 3)) * 2;
        bh8 a[2], b[8];
#pragma unroll
        for (int mf = 0; mf < 2; ++mf) {
          int row = (w << 5) + mf * 16 + (lane & 15);
          int ad = row * 128 + (kByte ^ ((row & 7) << 4));
          a[mf] = *reinterpret_cast<const bh8*>(reinterpret_cast<const char*>(As) + ad);
        }
#pragma unroll
        for (int nf = 0; nf < 8; ++nf) {
          int bn = nf * 16 + (lane & 15);
          int ad = bn * 128 + (kByte ^ ((bn & 7) << 4));
          b[nf] = *reinterpret_cast<const bh8*>(reinterpret_cast<const char*>(Bs) + ad);
        }
#pragma unroll
        for (int mf = 0; mf < 2; ++mf)
#pragma unroll
          for (int nf = 0; nf < 8; ++nf)
            acc[mf][nf] = __builtin_amdgcn_mfma_f32_16x16x32_bf16(a[mf], b[nf], acc[mf][nf], 0, 0, 0);
      }
      __syncthreads();
    }

    const int cb = n0 + (lane & 15);
#pragma unroll
    for (int mf = 0; mf < 2; ++mf) {
#pragma unroll
      for (int reg = 0; reg < 4; ++reg) {
        int grow = m0 + (w << 5) + mf * 16 + ((lane >> 4) << 2) + reg;
        if (grow < ne) {
          size_t hb = (size_t)(oe + grow) * HH;
#pragma unroll
          for (int nf = 0; nf < 4; ++nf) {
            float g = acc[mf][nf][reg];
            float u = acc[mf][nf + 4][reg];
            hbuf[hb + cb + nf * 16] = __float2bfloat16(silu_f(g) * u);
          }
        }
      }
    }
  }
}

// ---------------- GEMM2: ybuf[row] = score * (h_e * Wd_e) in bf16 ----------------
// Round-8 proven mapping (126us): same structure, atomic-free bf16 epilogue.
__global__ __launch_bounds__(256, 2) void k_gemm2(
    const __hip_bfloat16* __restrict__ hbuf,
    const __hip_bfloat16* __restrict__ Wdb,
    const float* __restrict__ rows_score,
    const int* __restrict__ off,
    __hip_bfloat16* __restrict__ ybuf) {
  const int e = blockIdx.z;
  const int oe = off[e];
  const int ne = off[e + 1] - oe;
  if (ne <= 0) return;
  const int n0 = blockIdx.x * 128;
  const int tid = threadIdx.x;
  const int lane = tid & 63;
  const int w = tid >> 6;

  __shared__ __hip_bfloat16 As[128 * 64];
  __shared__ __hip_bfloat16 Bs[128 * 64];
  const int kel = (((lane & 7) ^ (lane >> 3)) << 3);

  const __hip_bfloat16* bsrc[4];
#pragma unroll
  for (int i = 0; i < 4; ++i) {
    int bn = ((w * 4 + i) << 3) + (lane >> 3);
    bsrc[i] = Wdb + ((size_t)e * DD + (n0 + bn)) * HH + kel;
  }

  for (int m0 = blockIdx.y * 128; m0 < ne; m0 += gridDim.y * 128) {
    const __hip_bfloat16* asrc[4];
#pragma unroll
    for (int i = 0; i < 4; ++i) {
      int r = ((w * 4 + i) << 3) + (lane >> 3);
      int rr = m0 + r; rr = rr < ne ? rr : ne - 1;
      asrc[i] = hbuf + (size_t)(oe + rr) * HH + kel;
    }

    f4 acc[2][8];
#pragma unroll
    for (int mf = 0; mf < 2; ++mf)
#pragma unroll
      for (int nf = 0; nf < 8; ++nf)
        acc[mf][nf] = (f4){0.f, 0.f, 0.f, 0.f};

    for (int k0 = 0; k0 < HH; k0 += 64) {
#pragma unroll
      for (int i = 0; i < 4; ++i) {
        glds16(asrc[i] + k0, As + ((w * 4 + i) << 9));
        glds16(bsrc[i] + k0, Bs + ((w * 4 + i) << 9));
      }
      __syncthreads();
#pragma unroll
      for (int kk = 0; kk < 2; ++kk) {
        const int kByte = (kk * 32 + ((lane >> 4) << 3)) * 2;
        bh8 a[2], b[8];
#pragma unroll
        for (int mf = 0; mf < 2; ++mf) {
          int row = (w << 5) + mf * 16 + (lane & 15);
          int ad = row * 128 + (kByte ^ ((row & 7) << 4));
          a[mf] = *reinterpret_cast<const bh8*>(reinterpret_cast<const char*>(As) + ad);
        }
#pragma unroll
        for (int nf = 0; nf < 8; ++nf) {
          int bn = nf * 16 + (lane & 15);
          int ad = bn * 128 + (kByte ^ ((bn & 7) << 4));
          b[nf] = *reinterpret_cast<const bh8*>(reinterpret_cast<const char*>(Bs) + ad);
        }
#pragma unroll
        for (int mf = 0; mf < 2; ++mf)
#pragma unroll
          for (int nf = 0; nf < 8; ++nf)
            acc[mf][nf] = __builtin_amdgcn_mfma_f32_16x16x32_bf16(a[mf], b[nf], acc[mf][nf], 0, 0, 0);
      }
      __syncthreads();
    }

#pragma unroll
    for (int mf = 0; mf < 2; ++mf) {
#pragma unroll
      for (int reg = 0; reg < 4; ++reg) {
        int grow = m0 + (w << 5) + mf * 16 + ((lane >> 4) << 2) + reg;
        if (grow < ne) {
          float sc = rows_score[oe + grow];
          __hip_bfloat16* yr = ybuf + (size_t)(oe + grow) * DD + n0 + (lane & 15);
#pragma unroll
          for (int nf = 0; nf < 8; ++nf)
            yr[nf * 16] = __float2bfloat16(sc * acc[mf][nf][reg]);
        }
      }
    }
  }
}

// ---------------- launch ----------------
extern "C" void kernel_launch(void* const* d_in, const int* in_sizes, int n_in,
                              void* d_out, int out_size, void* d_ws, size_t ws_size,
                              hipStream_t stream) {
  const float* x = (const float*)d_in[0];
  const int* topk_idx = (const int*)d_in[1];
  const float* topk_sc = (const float*)d_in[2];
  const float* Wg = (const float*)d_in[3];
  const float* Wu = (const float*)d_in[4];
  const float* Wd = (const float*)d_in[5];
  float* y = (float*)d_out;

  char* p = (char*)d_ws;
  auto take = [&](size_t b) { char* r = p; p += (b + 255) & ~(size_t)255; return r; };
  int* off = (int*)take((EE + 1) * 4);
  int* rows_token = (int*)take((size_t)NA * 4);
  float* rows_score = (float*)take((size_t)NA * 4);
  int* pos = (int*)take((size_t)NA * 4);
  __hip_bfloat16* xb = (__hip_bfloat16*)take((size_t)TT * DD * 2);
  __hip_bfloat16* Wgb = (__hip_bfloat16*)take((size_t)EE * DD * HH * 2);
  __hip_bfloat16* Wub = (__hip_bfloat16*)take((size_t)EE * DD * HH * 2);
  __hip_bfloat16* Wdb = (__hip_bfloat16*)take((size_t)EE * DD * HH * 2);
  __hip_bfloat16* hbuf = (__hip_bfloat16*)take((size_t)NA * HH * 2);
  __hip_bfloat16* ybuf = (__hip_bfloat16*)take((size_t)NA * DD * 2);

  k_book<<<1, 1024, 0, stream>>>(topk_idx, topk_sc, off, rows_token, rows_score, pos);
  k_prep<<<9472, 256, 0, stream>>>(x, xb, Wg, Wu, Wd, Wgb, Wub, Wdb);
  k_gemm1<<<dim3(HH / 64, 17, EE), 256, 0, stream>>>(xb, Wgb, Wub, rows_token, off, hbuf);
  k_gemm2<<<dim3(DD / 128, 17, EE), 256, 0, stream>>>(hbuf, Wdb, rows_score, off, ybuf);
  k_combine<<<TT * (DD / 8) / 256, 256, 0, stream>>>(ybuf, pos, y);
}